// Round 4
// baseline (351.492 us; speedup 1.0000x reference)
//
#include <hip/hip_runtime.h>
#include <math.h>

#define NEG 0.2f
#define EPSV 1e-5f

typedef _Float16 v8h __attribute__((ext_vector_type(8)));
typedef _Float16 v4h __attribute__((ext_vector_type(4)));
typedef _Float16 v2h __attribute__((ext_vector_type(2)));
typedef __fp16   f16x2 __attribute__((ext_vector_type(2)));
typedef float    v4f __attribute__((ext_vector_type(4)));

__device__ __forceinline__ float lrelu(float v) { return fmaxf(v, NEG * v); }
__device__ __forceinline__ v4f lrelu4(v4f v) {
    return __builtin_elementwise_max(v, v * NEG);
}
__device__ __forceinline__ v2h lreluh2(v2h v) {
    return __builtin_elementwise_max(v, v * (_Float16)NEG);
}

// cvt_pkrtz returns __fp16x2; bit-cast to _Float16x2 (same layout)
__device__ __forceinline__ v2h pk(float a, float b) {
    union { f16x2 i; v2h o; } u;
    u.i = __builtin_amdgcn_cvt_pkrtz(a, b);
    return u.o;
}

#define MFMA16(a, b, c) __builtin_amdgcn_mfma_f32_16x16x16f16((a), (b), (c), 0, 0, 0)

// Round 18: the kernel is latency-bound at structurally-pinned occupancy.
// R17 counters: MfmaUtil 24.5, VALUBusy 56, neither pipe saturated; total
// waves = 65536 pts / 16 per wave = 4096 = 4 waves/SIMD (Occupancy ~31%).
// Serial MFMA chains (4-deep pos_enc) + gather loads can't be hidden by 4
// waves. num/den/cmx are sum/sum/max -> associative in k. So: split the 20-k
// reduction across wave pairs. Waves (0,2),(1,3) process the SAME 16 points,
// k in [0,10) vs [10,20); pair-combine through LDS at the end, reusing the
// weight-staging LDS region (no extra LDS). Blocks now cover 32 points;
// grid 2048 = 8 blocks/CU x 4 waves = 32 waves/CU = 8 waves/SIMD.
// __launch_bounds__(256,8): loop body already fits 64 VGPRs (R17 measured).
__global__ __launch_bounds__(256, 8)
void gsl_mfma(const float* __restrict__ x,
              const float* __restrict__ trans_w, const float* __restrict__ trans_g,
              const float* __restrict__ trans_b, const float* __restrict__ trans_m,
              const float* __restrict__ trans_v,
              const float* __restrict__ pos_w1, const float* __restrict__ pos_g,
              const float* __restrict__ pos_b, const float* __restrict__ pos_m,
              const float* __restrict__ pos_v, const float* __restrict__ pos_w2,
              const float* __restrict__ pos_b2,
              const float* __restrict__ gate_w1, const float* __restrict__ gate_g,
              const float* __restrict__ gate_b, const float* __restrict__ gate_m,
              const float* __restrict__ gate_v, const float* __restrict__ gate_w2,
              const float* __restrict__ gate_b2,
              const float* __restrict__ attn_w1, const float* __restrict__ attn_g,
              const float* __restrict__ attn_b, const float* __restrict__ attn_m,
              const float* __restrict__ attn_v, const float* __restrict__ attn_w2,
              const float* __restrict__ attn_b2,
              float* __restrict__ out)
{
    // manual LDS pool so the weight region can be reused as the combine buffer
    __shared__ __align__(16) char SMEM[14336];
    _Float16* const WH  = (_Float16*)SMEM;            // 1920 h = 3840 B
    _Float16* const W2L = (_Float16*)(SMEM + 3840);   // 5120 h = 10240 B
    float*    const PB2 = (float*)(SMEM + 14080);     // 64 f  = 256 B

    const int tid  = threadIdx.x;
    const int wv   = tid >> 6;
    const int lane = tid & 63;
    const int p    = lane & 15;
    const int q    = lane >> 4;

    const int pw = wv & 1;    // point group within block
    const int kh = wv >> 1;   // k-half: 0 -> [0,10), 1 -> [10,20)

    const int b  = blockIdx.x >> 8;                       // 2048 blocks: 256/b
    const int n0 = ((blockIdx.x & 255) << 5) | (pw << 4); // 32 points per block
    const int n  = n0 | p;

    // ---- stage pos_w2 A-frags into W2L ----
    // lane(p,q) v8h at tile*640 + p*40 + 8q; element ii maps to source col
    //   c = (t&1)*32 + ((ii&7)>>2)*16 + ((ii>>3)<<2) + (ii&3)
    // so v8h lo4 = A_ck(2h)[p][4q+i], hi4 = A_ck(2h+1)[p][4q+i].
    #pragma unroll
    for (int e = 0; e < 16; ++e) {
        int idx = tid * 16 + e;              // 4096 elements
        int t   = idx >> 9;                  // tile (mt*2+h)
        int rem = idx & 511;
        int pp  = rem >> 5;
        int ii  = rem & 31;
        int c   = (t & 1) * 32 + ((ii & 7) >> 2) * 16 + ((ii >> 3) << 2) + (ii & 3);
        W2L[t * 640 + pp * 40 + ii] =
            (_Float16)pos_w2[((t >> 1) * 16 + pp) * 64 + c];
    }

    // ---- stage produce-side weights in block-shared LDS (rows stride 20h) ----
    if (tid < 64) {
        const int c = tid;
        float sp = pos_g[c] * rsqrtf(pos_v[c] + EPSV);
        float bp = pos_b[c] - pos_m[c] * sp;
        _Float16* row = WH + (c >> 4) * 320 + (c & 15) * 20;
        for (int k = 0; k < 20; ++k) {
            float v = (k >= 3 && k < 6) ? pos_w1[c * 3 + (k - 3)] * sp
                                        : ((k == 6) ? bp : 0.f);
            row[k] = (_Float16)v;
        }
        PB2[c] = pos_b2[c];
    } else if (tid < 80) {
        const int j = tid - 64;
        float sa = attn_g[j] * rsqrtf(attn_v[j] + EPSV);
        float ba = attn_b[j] - attn_m[j] * sa;
        _Float16* row = WH + 1280 + j * 20;
        for (int k = 0; k < 20; ++k)
            row[k] = (_Float16)((k < 6) ? attn_w1[j * 6 + k] * sa
                                        : ((k == 6) ? ba : 0.f));
    } else if (tid < 96) {
        const int j = tid - 80;
        float sg = gate_g[j] * rsqrtf(gate_v[j] + EPSV);
        float bg = gate_b[j] - gate_m[j] * sg;
        _Float16* row = WH + 1600 + j * 20;
        for (int k = 0; k < 20; ++k)
            row[k] = (_Float16)((k < 6) ? gate_w1[j * 6 + k] * sg
                                        : ((k == 6) ? bg : 0.f));
    }

    // ---- persistent A-frags: WTf/WA2f (2 VGPRs each) + WG2f broadcast ----
    v4h WTf[4], WA2f[4], WG2f;
    #pragma unroll
    for (int mt = 0; mt < 4; ++mt) {
        const int ch = mt * 16 + p;
        #pragma unroll
        for (int i = 0; i < 4; ++i)
            WA2f[mt][i] = (_Float16)attn_w2[ch * 16 + q * 4 + i];
        float st = trans_g[ch] * rsqrtf(trans_v[ch] + EPSV);
        float bt = trans_b[ch] - trans_m[ch] * st;
        #pragma unroll
        for (int i = 0; i < 4; ++i) {
            int k = q * 4 + i;
            float v = (k < 6) ? trans_w[ch * 6 + k] * st : ((k == 6) ? bt : 0.f);
            WTf[mt][i] = (_Float16)v;
        }
    }
    #pragma unroll
    for (int i = 0; i < 4; ++i)
        WG2f[i] = (_Float16)gate_w2[4 * q + i];   // A[row][k]=gate_w2[k] broadcast
    const float gb2v = gate_b2[0];

    __syncthreads();   // W2L/WH/PB2 visible to all waves

    const _Float16* const WP1p = WH + p * 20 + q * 4;          // + mt*320
    const _Float16* const WA1p = WH + 1280 + p * 20 + q * 4;
    const _Float16* const WG1p = WH + 1600 + p * 20 + q * 4;
    const _Float16* const W2Lp = W2L + p * 40 + q * 8;         // + tile*640
    const float* const    PB2p = PB2 + 4 * q;                  // + mt*16

    const v4f zero = {0.f, 0.f, 0.f, 0.f};
    v4f den[4], num[4], cmx[4];
    #pragma unroll
    for (int mt = 0; mt < 4; ++mt) {
        den[mt] = zero; num[mt] = zero;
        cmx[mt] = (v4f){-3.4e38f, -3.4e38f, -3.4e38f, -3.4e38f};
    }

    // ---- per-lane channel streams (only the 4 this lane consumes) ----
    const float* xb = x + ((size_t)(b * 6) * 8192 + n) * 20;
    const int hi = q & 1;   // q>=2 dups q&1 (A-side k>=8 rows are zero)
    const float* const s0p = xb + (size_t)(hi ? 4 : 0) * 163840;
    const float* const s1p = xb + (size_t)(hi ? 5 : 1) * 163840;
    const float* const s2p = xb + (size_t)(hi ? 4 : 2) * 163840;  // hi: L1 dup
    const float* const s3p = xb + (size_t)(hi ? 5 : 3) * 163840;  // hi: L1 dup

    // build v4h B-frag; hi lanes' high half is the constant (1.0, 0.0)
    auto mk = [&](float a, float bb, float cc, float dd) -> v4h {
        v2h lo = pk(a, bb);
        v2h hh = pk(cc, dd);
        if (hi) { union { unsigned u; v2h h; } t; t.u = 0x00003C00u; hh = t.h; }
        return (v4h){lo.x, lo.y, hh.x, hh.y};
    };

    const int k0 = kh * 10;   // this wave's k range: [k0, k0+10)
    float c0 = s0p[k0], c1 = s1p[k0], c2 = s2p[k0], c3 = s3p[k0];

    #pragma unroll 1
    for (int j = 0; j < 10; ++j) {
        // prevent LICM from hoisting in-loop LDS reads into registers
        asm volatile("" ::: "memory");

        v4h xv = mk(c0, c1, c2, c3);
        if (j < 9) {
            const int kn = k0 + j + 1;
            c0 = s0p[kn]; c1 = s1p[kn]; c2 = s2p[kn]; c3 = s3p[kn];
        }

        // ---- hidden layers: MFMA outputs stay in registers (C==B layout) ----
        v4h phB[4];
        #pragma unroll
        for (int mt = 0; mt < 4; ++mt) {
            v4f php = MFMA16(*(const v4h*)(WP1p + mt * 320), xv, zero);
            union { v4h v; v2h h[2]; } u;
            u.h[0] = lreluh2(pk(php[0], php[1]));
            u.h[1] = lreluh2(pk(php[2], php[3]));
            phB[mt] = u.v;
        }
        v4f ahp = MFMA16(*(const v4h*)WA1p, xv, zero);
        union { v4h v; v2h h[2]; } ua;
        ua.h[0] = lreluh2(pk(ahp[0], ahp[1]));
        ua.h[1] = lreluh2(pk(ahp[2], ahp[3]));
        const v4h ahB = ua.v;

        // gate: MFMA reduction (broadcast A) -> every lane gets its col's logit
        v4f ghp = MFMA16(*(const v4h*)WG1p, xv, zero);
        union { v4h v; v2h h[2]; } ug;
        ug.h[0] = lreluh2(pk(ghp[0], ghp[1]));
        ug.h[1] = lreluh2(pk(ghp[2], ghp[3]));
        v4f gav = MFMA16(WG2f, ug.v, zero);
        const float gate = 1.f / (1.f + __expf(-(gav[0] + gb2v)));

        // ---- consume: pos_enc as 4x K=16 MFMA chain per output tile ----
        #pragma unroll
        for (int mt = 0; mt < 4; ++mt) {
            union { v8h v; v4h h[2]; } w2a, w2b;
            w2a.v = *(const v8h*)(W2Lp + (mt * 2 + 0) * 640);  // ck0 | ck1
            w2b.v = *(const v8h*)(W2Lp + (mt * 2 + 1) * 640);  // ck2 | ck3
            v4f pe = MFMA16(w2a.h[0], phB[0], *(const v4f*)(PB2p + mt * 16));
            pe = MFMA16(w2a.h[1], phB[1], pe);
            pe = MFMA16(w2b.h[0], phB[2], pe);
            pe = MFMA16(w2b.h[1], phB[3], pe);
            v4f tfa = MFMA16(WTf[mt], xv, zero);
            v4f tfv = lrelu4(tfa) + pe;
            pe = MFMA16(WA2f[mt], ahB, pe);   // attn logits (K=16)
            v4f e;
            #pragma unroll
            for (int r = 0; r < 4; ++r) e[r] = __expf(pe[r]);
            den[mt] += e;
            num[mt] += tfv * e;
            cmx[mt] = __builtin_elementwise_max(cmx[mt], tfv * gate);
        }
    }

    // ---- pair-combine: waves (0,2) and (1,3) share a point set ----
    // reuse the weight-staging LDS as the exchange buffer (12,288 B <= 14,336)
    __syncthreads();                      // all loop reads of WH/W2L done
    float* const XBUF = (float*)SMEM;     // 64 lanes x 48 f32

    if (wv == 2) {
        float* dst = XBUF + lane * 48;
        #pragma unroll
        for (int mt = 0; mt < 4; ++mt) {
            *(v4f*)(dst + mt * 4)      = den[mt];
            *(v4f*)(dst + 16 + mt * 4) = num[mt];
            *(v4f*)(dst + 32 + mt * 4) = cmx[mt];
        }
    }
    __syncthreads();
    if (wv == 0) {
        const float* src = XBUF + lane * 48;
        #pragma unroll
        for (int mt = 0; mt < 4; ++mt) {
            den[mt] += *(const v4f*)(src + mt * 4);
            num[mt] += *(const v4f*)(src + 16 + mt * 4);
            cmx[mt] = __builtin_elementwise_max(cmx[mt],
                        *(const v4f*)(src + 32 + mt * 4));
        }
    }
    __syncthreads();
    if (wv == 3) {
        float* dst = XBUF + lane * 48;
        #pragma unroll
        for (int mt = 0; mt < 4; ++mt) {
            *(v4f*)(dst + mt * 4)      = den[mt];
            *(v4f*)(dst + 16 + mt * 4) = num[mt];
            *(v4f*)(dst + 32 + mt * 4) = cmx[mt];
        }
    }
    __syncthreads();
    if (wv == 1) {
        const float* src = XBUF + lane * 48;
        #pragma unroll
        for (int mt = 0; mt < 4; ++mt) {
            den[mt] += *(const v4f*)(src + mt * 4);
            num[mt] += *(const v4f*)(src + 16 + mt * 4);
            cmx[mt] = __builtin_elementwise_max(cmx[mt],
                        *(const v4f*)(src + 32 + mt * 4));
        }
    }

    // write out: waves 0,1 own the two point groups; lane owns channels
    // mt*16 + 4q + r for its point n
    if (wv < 2) {
        #pragma unroll
        for (int mt = 0; mt < 4; ++mt) {
            #pragma unroll
            for (int r = 0; r < 4; ++r) {
                const int ch = mt * 16 + 4 * q + r;
                out[((size_t)(b * 64 + ch)) * 8192 + n] =
                    num[mt][r] / den[mt][r] + cmx[mt][r];
            }
        }
    }
}

extern "C" void kernel_launch(void* const* d_in, const int* in_sizes, int n_in,
                              void* d_out, int out_size, void* d_ws, size_t ws_size,
                              hipStream_t stream) {
    const float* x       = (const float*)d_in[0];
    const float* trans_w = (const float*)d_in[1];
    const float* trans_g = (const float*)d_in[2];
    const float* trans_b = (const float*)d_in[3];
    const float* trans_m = (const float*)d_in[4];
    const float* trans_v = (const float*)d_in[5];
    const float* pos_w1  = (const float*)d_in[6];
    const float* pos_g   = (const float*)d_in[7];
    const float* pos_b   = (const float*)d_in[8];
    const float* pos_m   = (const float*)d_in[9];
    const float* pos_v   = (const float*)d_in[10];
    const float* pos_w2  = (const float*)d_in[11];
    const float* pos_b2  = (const float*)d_in[12];
    const float* gate_w1 = (const float*)d_in[13];
    const float* gate_g  = (const float*)d_in[14];
    const float* gate_b  = (const float*)d_in[15];
    const float* gate_m  = (const float*)d_in[16];
    const float* gate_v  = (const float*)d_in[17];
    const float* gate_w2 = (const float*)d_in[18];
    const float* gate_b2 = (const float*)d_in[19];
    const float* attn_w1 = (const float*)d_in[20];
    const float* attn_g  = (const float*)d_in[21];
    const float* attn_b  = (const float*)d_in[22];
    const float* attn_m  = (const float*)d_in[23];
    const float* attn_v  = (const float*)d_in[24];
    const float* attn_w2 = (const float*)d_in[25];
    const float* attn_b2 = (const float*)d_in[26];
    float* out = (float*)d_out;

    // 8 b * 256 blocks/b; block = 4 waves: 2 point-groups x 2 k-halves
    gsl_mfma<<<2048, 256, 0, stream>>>(
        x, trans_w, trans_g, trans_b, trans_m, trans_v,
        pos_w1, pos_g, pos_b, pos_m, pos_v, pos_w2, pos_b2,
        gate_w1, gate_g, gate_b, gate_m, gate_v, gate_w2, gate_b2,
        attn_w1, attn_g, attn_b, attn_m, attn_v, attn_w2, attn_b2,
        out);
}

// Round 5
// 189.234 us; speedup vs baseline: 1.8575x; 1.8575x over previous
//
#include <hip/hip_runtime.h>
#include <math.h>

#define NEG 0.2f
#define EPSV 1e-5f

typedef _Float16 v8h __attribute__((ext_vector_type(8)));
typedef _Float16 v4h __attribute__((ext_vector_type(4)));
typedef _Float16 v2h __attribute__((ext_vector_type(2)));
typedef __fp16   f16x2 __attribute__((ext_vector_type(2)));
typedef float    v4f __attribute__((ext_vector_type(4)));

__device__ __forceinline__ float lrelu(float v) { return fmaxf(v, NEG * v); }
__device__ __forceinline__ v4f lrelu4(v4f v) {
    return __builtin_elementwise_max(v, v * NEG);
}
__device__ __forceinline__ v2h lreluh2(v2h v) {
    return __builtin_elementwise_max(v, v * (_Float16)NEG);
}

// cvt_pkrtz returns __fp16x2; bit-cast to _Float16x2 (same layout)
__device__ __forceinline__ v2h pk(float a, float b) {
    union { f16x2 i; v2h o; } u;
    u.i = __builtin_amdgcn_cvt_pkrtz(a, b);
    return u.o;
}

#define MFMA16(a, b, c) __builtin_amdgcn_mfma_f32_16x16x16f16((a), (b), (c), 0, 0, 0)

// Round 19: retry R18's k-split TLP at a FEASIBLE register point.
// R18 failed because gfx950's unified VGPR/AGPR file makes (256,8) a 64-reg
// TOTAL budget; accumulators alone are 48 -> catastrophic spill (FETCH 551MB).
// This round: __launch_bounds__(256,5) -> 102 regs/wave budget, and the
// persistent WTf/WA2f A-frags (16 VGPRs, constant per lane) move to LDS
// (staged once by wave 0, re-read per iter; asm clobber keeps them there).
// Live state ~ 48 acc + ~46 arch <= 102. Grid 2048, 4-wave blocks covering
// 32 points x 2 k-halves; pair-combine through LDS (verified in R18).
// 5 blocks/CU resident -> 20 waves/CU (vs 16) and halved per-wave runtime.
// Spill tripwire: WRITE_SIZE must stay ~16.4MB.
__global__ __launch_bounds__(256, 5)
void gsl_mfma(const float* __restrict__ x,
              const float* __restrict__ trans_w, const float* __restrict__ trans_g,
              const float* __restrict__ trans_b, const float* __restrict__ trans_m,
              const float* __restrict__ trans_v,
              const float* __restrict__ pos_w1, const float* __restrict__ pos_g,
              const float* __restrict__ pos_b, const float* __restrict__ pos_m,
              const float* __restrict__ pos_v, const float* __restrict__ pos_w2,
              const float* __restrict__ pos_b2,
              const float* __restrict__ gate_w1, const float* __restrict__ gate_g,
              const float* __restrict__ gate_b, const float* __restrict__ gate_m,
              const float* __restrict__ gate_v, const float* __restrict__ gate_w2,
              const float* __restrict__ gate_b2,
              const float* __restrict__ attn_w1, const float* __restrict__ attn_g,
              const float* __restrict__ attn_b, const float* __restrict__ attn_m,
              const float* __restrict__ attn_v, const float* __restrict__ attn_w2,
              const float* __restrict__ attn_b2,
              float* __restrict__ out)
{
    // manual LDS pool:
    //   0     : WH   (1920 h = 3840 B)
    //   3840  : W2L  (5120 h = 10240 B)
    //   14080 : PB2  (64 f  = 256 B)
    //   14336 : WTL  (4 mt x 64 lanes x v4h = 2048 B)
    //   16384 : WA2L (2048 B)
    // XBUF (combine) reuses [0, 13312) after the loop.
    __shared__ __align__(16) char SMEM[18432];
    _Float16* const WH   = (_Float16*)SMEM;
    _Float16* const W2L  = (_Float16*)(SMEM + 3840);
    float*    const PB2  = (float*)(SMEM + 14080);
    _Float16* const WTL  = (_Float16*)(SMEM + 14336);
    _Float16* const WA2L = (_Float16*)(SMEM + 16384);

    const int tid  = threadIdx.x;
    const int wv   = tid >> 6;
    const int lane = tid & 63;
    const int p    = lane & 15;
    const int q    = lane >> 4;

    const int pw = wv & 1;    // point group within block
    const int kh = wv >> 1;   // k-half: 0 -> [0,10), 1 -> [10,20)

    const int b  = blockIdx.x >> 8;                       // 2048 blocks: 256/b
    const int n0 = ((blockIdx.x & 255) << 5) | (pw << 4); // 32 points per block
    const int n  = n0 | p;

    // ---- stage pos_w2 A-frags into W2L ----
    // lane(p,q) v8h at tile*640 + p*40 + 8q; element ii maps to source col
    //   c = (t&1)*32 + ((ii&7)>>2)*16 + ((ii>>3)<<2) + (ii&3)
    // so v8h lo4 = A_ck(2h)[p][4q+i], hi4 = A_ck(2h+1)[p][4q+i].
    #pragma unroll
    for (int e = 0; e < 16; ++e) {
        int idx = tid * 16 + e;              // 4096 elements
        int t   = idx >> 9;                  // tile (mt*2+h)
        int rem = idx & 511;
        int pp  = rem >> 5;
        int ii  = rem & 31;
        int c   = (t & 1) * 32 + ((ii & 7) >> 2) * 16 + ((ii >> 3) << 2) + (ii & 3);
        W2L[t * 640 + pp * 40 + ii] =
            (_Float16)pos_w2[((t >> 1) * 16 + pp) * 64 + c];
    }

    // ---- stage produce-side weights in block-shared LDS (rows stride 20h) ----
    if (tid < 64) {
        const int c = tid;
        float sp = pos_g[c] * rsqrtf(pos_v[c] + EPSV);
        float bp = pos_b[c] - pos_m[c] * sp;
        _Float16* row = WH + (c >> 4) * 320 + (c & 15) * 20;
        for (int k = 0; k < 20; ++k) {
            float v = (k >= 3 && k < 6) ? pos_w1[c * 3 + (k - 3)] * sp
                                        : ((k == 6) ? bp : 0.f);
            row[k] = (_Float16)v;
        }
        PB2[c] = pos_b2[c];
    } else if (tid < 80) {
        const int j = tid - 64;
        float sa = attn_g[j] * rsqrtf(attn_v[j] + EPSV);
        float ba = attn_b[j] - attn_m[j] * sa;
        _Float16* row = WH + 1280 + j * 20;
        for (int k = 0; k < 20; ++k)
            row[k] = (_Float16)((k < 6) ? attn_w1[j * 6 + k] * sa
                                        : ((k == 6) ? ba : 0.f));
    } else if (tid < 96) {
        const int j = tid - 80;
        float sg = gate_g[j] * rsqrtf(gate_v[j] + EPSV);
        float bg = gate_b[j] - gate_m[j] * sg;
        _Float16* row = WH + 1600 + j * 20;
        for (int k = 0; k < 20; ++k)
            row[k] = (_Float16)((k < 6) ? gate_w1[j * 6 + k] * sg
                                        : ((k == 6) ? bg : 0.f));
    }

    // ---- stage WTf/WA2f per-lane A-frags into LDS (wave 0 only) ----
    if (wv == 0) {
        #pragma unroll
        for (int mt = 0; mt < 4; ++mt) {
            const int ch = mt * 16 + p;
            v4h wa, wt;
            #pragma unroll
            for (int i = 0; i < 4; ++i)
                wa[i] = (_Float16)attn_w2[ch * 16 + q * 4 + i];
            float st = trans_g[ch] * rsqrtf(trans_v[ch] + EPSV);
            float bt = trans_b[ch] - trans_m[ch] * st;
            #pragma unroll
            for (int i = 0; i < 4; ++i) {
                int k = q * 4 + i;
                float v = (k < 6) ? trans_w[ch * 6 + k] * st
                                  : ((k == 6) ? bt : 0.f);
                wt[i] = (_Float16)v;
            }
            *(v4h*)(WTL  + (mt * 64 + lane) * 4) = wt;
            *(v4h*)(WA2L + (mt * 64 + lane) * 4) = wa;
        }
    }

    // gate second-layer broadcast A-frag: tiny, keep in regs
    v4h WG2f;
    #pragma unroll
    for (int i = 0; i < 4; ++i)
        WG2f[i] = (_Float16)gate_w2[4 * q + i];
    const float gb2v = gate_b2[0];

    __syncthreads();   // all LDS staging visible

    const _Float16* const WP1p = WH + p * 20 + q * 4;          // + mt*320
    const _Float16* const WA1p = WH + 1280 + p * 20 + q * 4;
    const _Float16* const WG1p = WH + 1600 + p * 20 + q * 4;
    const _Float16* const W2Lp = W2L + p * 40 + q * 8;         // + tile*640
    const float* const    PB2p = PB2 + 4 * q;                  // + mt*16
    const _Float16* const WTp  = WTL  + lane * 4;              // + mt*256
    const _Float16* const WA2p = WA2L + lane * 4;              // + mt*256

    const v4f zero = {0.f, 0.f, 0.f, 0.f};
    v4f den[4], num[4], cmx[4];
    #pragma unroll
    for (int mt = 0; mt < 4; ++mt) {
        den[mt] = zero; num[mt] = zero;
        cmx[mt] = (v4f){-3.4e38f, -3.4e38f, -3.4e38f, -3.4e38f};
    }

    // ---- per-lane channel streams (only the 4 this lane consumes) ----
    const float* xb = x + ((size_t)(b * 6) * 8192 + n) * 20;
    const int hi = q & 1;   // q>=2 dups q&1 (A-side k>=8 rows are zero)
    const float* const s0p = xb + (size_t)(hi ? 4 : 0) * 163840;
    const float* const s1p = xb + (size_t)(hi ? 5 : 1) * 163840;
    const float* const s2p = xb + (size_t)(hi ? 4 : 2) * 163840;  // hi: L1 dup
    const float* const s3p = xb + (size_t)(hi ? 5 : 3) * 163840;  // hi: L1 dup

    // build v4h B-frag; hi lanes' high half is the constant (1.0, 0.0)
    auto mk = [&](float a, float bb, float cc, float dd) -> v4h {
        v2h lo = pk(a, bb);
        v2h hh = pk(cc, dd);
        if (hi) { union { unsigned u; v2h h; } t; t.u = 0x00003C00u; hh = t.h; }
        return (v4h){lo.x, lo.y, hh.x, hh.y};
    };

    const int k0 = kh * 10;   // this wave's k range: [k0, k0+10)
    float c0 = s0p[k0], c1 = s1p[k0], c2 = s2p[k0], c3 = s3p[k0];

    #pragma unroll 1
    for (int j = 0; j < 10; ++j) {
        // prevent LICM from hoisting in-loop LDS reads into registers
        asm volatile("" ::: "memory");

        v4h xv = mk(c0, c1, c2, c3);
        if (j < 9) {
            const int kn = k0 + j + 1;
            c0 = s0p[kn]; c1 = s1p[kn]; c2 = s2p[kn]; c3 = s3p[kn];
        }

        // ---- hidden layers: MFMA outputs stay in registers (C==B layout) ----
        v4h phB[4];
        #pragma unroll
        for (int mt = 0; mt < 4; ++mt) {
            v4f php = MFMA16(*(const v4h*)(WP1p + mt * 320), xv, zero);
            union { v4h v; v2h h[2]; } u;
            u.h[0] = lreluh2(pk(php[0], php[1]));
            u.h[1] = lreluh2(pk(php[2], php[3]));
            phB[mt] = u.v;
        }
        v4f ahp = MFMA16(*(const v4h*)WA1p, xv, zero);
        union { v4h v; v2h h[2]; } ua;
        ua.h[0] = lreluh2(pk(ahp[0], ahp[1]));
        ua.h[1] = lreluh2(pk(ahp[2], ahp[3]));
        const v4h ahB = ua.v;

        // gate: MFMA reduction (broadcast A) -> every lane gets its col's logit
        v4f ghp = MFMA16(*(const v4h*)WG1p, xv, zero);
        union { v4h v; v2h h[2]; } ug;
        ug.h[0] = lreluh2(pk(ghp[0], ghp[1]));
        ug.h[1] = lreluh2(pk(ghp[2], ghp[3]));
        v4f gav = MFMA16(WG2f, ug.v, zero);
        const float gate = 1.f / (1.f + __expf(-(gav[0] + gb2v)));

        // ---- consume: pos_enc as 4x K=16 MFMA chain per output tile ----
        #pragma unroll
        for (int mt = 0; mt < 4; ++mt) {
            union { v8h v; v4h h[2]; } w2a, w2b;
            w2a.v = *(const v8h*)(W2Lp + (mt * 2 + 0) * 640);  // ck0 | ck1
            w2b.v = *(const v8h*)(W2Lp + (mt * 2 + 1) * 640);  // ck2 | ck3
            v4f pe = MFMA16(w2a.h[0], phB[0], *(const v4f*)(PB2p + mt * 16));
            pe = MFMA16(w2a.h[1], phB[1], pe);
            pe = MFMA16(w2b.h[0], phB[2], pe);
            pe = MFMA16(w2b.h[1], phB[3], pe);
            v4f tfa = MFMA16(*(const v4h*)(WTp + mt * 256), xv, zero);
            v4f tfv = lrelu4(tfa) + pe;
            pe = MFMA16(*(const v4h*)(WA2p + mt * 256), ahB, pe); // logits
            v4f e;
            #pragma unroll
            for (int r = 0; r < 4; ++r) e[r] = __expf(pe[r]);
            den[mt] += e;
            num[mt] += tfv * e;
            cmx[mt] = __builtin_elementwise_max(cmx[mt], tfv * gate);
        }
    }

    // ---- pair-combine: waves (0,2) and (1,3) share a point set ----
    // reuse staging LDS as exchange buffer; stride 52 floats (bank-friendly)
    __syncthreads();                      // all loop reads of LDS done
    float* const XBUF = (float*)SMEM;     // 64 lanes x 52 f32 = 13312 B

    if (wv == 2) {
        float* dst = XBUF + lane * 52;
        #pragma unroll
        for (int mt = 0; mt < 4; ++mt) {
            *(v4f*)(dst + mt * 4)      = den[mt];
            *(v4f*)(dst + 16 + mt * 4) = num[mt];
            *(v4f*)(dst + 32 + mt * 4) = cmx[mt];
        }
    }
    __syncthreads();
    if (wv == 0) {
        const float* src = XBUF + lane * 52;
        #pragma unroll
        for (int mt = 0; mt < 4; ++mt) {
            den[mt] += *(const v4f*)(src + mt * 4);
            num[mt] += *(const v4f*)(src + 16 + mt * 4);
            cmx[mt] = __builtin_elementwise_max(cmx[mt],
                        *(const v4f*)(src + 32 + mt * 4));
        }
    }
    __syncthreads();
    if (wv == 3) {
        float* dst = XBUF + lane * 52;
        #pragma unroll
        for (int mt = 0; mt < 4; ++mt) {
            *(v4f*)(dst + mt * 4)      = den[mt];
            *(v4f*)(dst + 16 + mt * 4) = num[mt];
            *(v4f*)(dst + 32 + mt * 4) = cmx[mt];
        }
    }
    __syncthreads();
    if (wv == 1) {
        const float* src = XBUF + lane * 52;
        #pragma unroll
        for (int mt = 0; mt < 4; ++mt) {
            den[mt] += *(const v4f*)(src + mt * 4);
            num[mt] += *(const v4f*)(src + 16 + mt * 4);
            cmx[mt] = __builtin_elementwise_max(cmx[mt],
                        *(const v4f*)(src + 32 + mt * 4));
        }
    }

    // write out: waves 0,1 own the two point groups; lane owns channels
    // mt*16 + 4q + r for its point n
    if (wv < 2) {
        #pragma unroll
        for (int mt = 0; mt < 4; ++mt) {
            #pragma unroll
            for (int r = 0; r < 4; ++r) {
                const int ch = mt * 16 + 4 * q + r;
                out[((size_t)(b * 64 + ch)) * 8192 + n] =
                    num[mt][r] / den[mt][r] + cmx[mt][r];
            }
        }
    }
}

extern "C" void kernel_launch(void* const* d_in, const int* in_sizes, int n_in,
                              void* d_out, int out_size, void* d_ws, size_t ws_size,
                              hipStream_t stream) {
    const float* x       = (const float*)d_in[0];
    const float* trans_w = (const float*)d_in[1];
    const float* trans_g = (const float*)d_in[2];
    const float* trans_b = (const float*)d_in[3];
    const float* trans_m = (const float*)d_in[4];
    const float* trans_v = (const float*)d_in[5];
    const float* pos_w1  = (const float*)d_in[6];
    const float* pos_g   = (const float*)d_in[7];
    const float* pos_b   = (const float*)d_in[8];
    const float* pos_m   = (const float*)d_in[9];
    const float* pos_v   = (const float*)d_in[10];
    const float* pos_w2  = (const float*)d_in[11];
    const float* pos_b2  = (const float*)d_in[12];
    const float* gate_w1 = (const float*)d_in[13];
    const float* gate_g  = (const float*)d_in[14];
    const float* gate_b  = (const float*)d_in[15];
    const float* gate_m  = (const float*)d_in[16];
    const float* gate_v  = (const float*)d_in[17];
    const float* gate_w2 = (const float*)d_in[18];
    const float* gate_b2 = (const float*)d_in[19];
    const float* attn_w1 = (const float*)d_in[20];
    const float* attn_g  = (const float*)d_in[21];
    const float* attn_b  = (const float*)d_in[22];
    const float* attn_m  = (const float*)d_in[23];
    const float* attn_v  = (const float*)d_in[24];
    const float* attn_w2 = (const float*)d_in[25];
    const float* attn_b2 = (const float*)d_in[26];
    float* out = (float*)d_out;

    // 8 b * 256 blocks/b; block = 4 waves: 2 point-groups x 2 k-halves
    gsl_mfma<<<2048, 256, 0, stream>>>(
        x, trans_w, trans_g, trans_b, trans_m, trans_v,
        pos_w1, pos_g, pos_b, pos_m, pos_v, pos_w2, pos_b2,
        gate_w1, gate_g, gate_b, gate_m, gate_v, gate_w2, gate_b2,
        attn_w1, attn_g, attn_b, attn_m, attn_v, attn_w2, attn_b2,
        out);
}

// Round 6
// 182.330 us; speedup vs baseline: 1.9278x; 1.0379x over previous
//
#include <hip/hip_runtime.h>
#include <math.h>

#define NEG 0.2f
#define EPSV 1e-5f

typedef _Float16 v8h __attribute__((ext_vector_type(8)));
typedef _Float16 v4h __attribute__((ext_vector_type(4)));
typedef _Float16 v2h __attribute__((ext_vector_type(2)));
typedef __fp16   f16x2 __attribute__((ext_vector_type(2)));
typedef float    v4f __attribute__((ext_vector_type(4)));

__device__ __forceinline__ float lrelu(float v) { return fmaxf(v, NEG * v); }
__device__ __forceinline__ v4f lrelu4(v4f v) {
    return __builtin_elementwise_max(v, v * NEG);
}
__device__ __forceinline__ v2h lreluh2(v2h v) {
    return __builtin_elementwise_max(v, v * (_Float16)NEG);
}

// cvt_pkrtz returns __fp16x2; bit-cast to _Float16x2 (same layout)
__device__ __forceinline__ v2h pk(float a, float b) {
    union { f16x2 i; v2h o; } u;
    u.i = __builtin_amdgcn_cvt_pkrtz(a, b);
    return u.o;
}

#define MFMA16(a, b, c) __builtin_amdgcn_mfma_f32_16x16x16f16((a), (b), (c), 0, 0, 0)

// Round 20: base = R17 (67.5us, VGPR 64, clean traffic). R18/R19 proved more
// waves/SIMD is infeasible (register-pinned at 4; spills at 5+). Span math:
// 160K cyc/SIMD for 20 iters = ~8K cyc/iter vs ~1K of issue work -> the
// kernel is DEPENDENCY-LATENCY bound on the serial 6-deep MFMA chain
// (hidden -> pack -> 4x pos_enc chain -> logits -> exp).
// Fix: MFMA reduction tree per mt, depth 6 -> 2:
//   peA = W2a0*phB0+PB2 -> W2a1*phB1   (depth 2)
//   peB = W2b0*phB2     -> W2b1*phB3   (depth 2, parallel)
//   la  = WA2*ahB ; tfa = WT*xv        (depth 1, parallel)
//   posenc = peA+peB; tfv = lrelu(tfa)+posenc; logits = posenc+la
// +8 VALU per mt (~64 cyc/iter issue) buys ~200+ cyc/iter latency.
// No new live state: transients only; (256,4) bounds as R17.
__global__ __launch_bounds__(256, 4)
void gsl_mfma(const float* __restrict__ x,
              const float* __restrict__ trans_w, const float* __restrict__ trans_g,
              const float* __restrict__ trans_b, const float* __restrict__ trans_m,
              const float* __restrict__ trans_v,
              const float* __restrict__ pos_w1, const float* __restrict__ pos_g,
              const float* __restrict__ pos_b, const float* __restrict__ pos_m,
              const float* __restrict__ pos_v, const float* __restrict__ pos_w2,
              const float* __restrict__ pos_b2,
              const float* __restrict__ gate_w1, const float* __restrict__ gate_g,
              const float* __restrict__ gate_b, const float* __restrict__ gate_m,
              const float* __restrict__ gate_v, const float* __restrict__ gate_w2,
              const float* __restrict__ gate_b2,
              const float* __restrict__ attn_w1, const float* __restrict__ attn_g,
              const float* __restrict__ attn_b, const float* __restrict__ attn_m,
              const float* __restrict__ attn_v, const float* __restrict__ attn_w2,
              const float* __restrict__ attn_b2,
              float* __restrict__ out)
{
    __shared__ _Float16 WH[1920];   // WP1 4x(16x20) | WA1 16x20 | WG1 16x20
    __shared__ _Float16 W2L[5120];  // pos_w2: 8 tiles x 16p x stride40,
                                    // inner 32 elems permuted into 2x K=16 A-frags
    __shared__ float    PB2[64];

    const int tid  = threadIdx.x;
    const int wv   = tid >> 6;
    const int lane = tid & 63;
    const int p    = lane & 15;
    const int q    = lane >> 4;

    const int b  = blockIdx.x >> 7;
    const int n0 = ((blockIdx.x & 127) << 6) | (wv << 4);
    const int n  = n0 | p;

    // ---- stage pos_w2 A-frags into W2L ----
    // lane(p,q) v8h at tile*640 + p*40 + 8q; element ii maps to source col
    //   c = (t&1)*32 + ((ii&7)>>2)*16 + ((ii>>3)<<2) + (ii&3)
    // so v8h lo4 = A_ck(2h)[p][4q+i], hi4 = A_ck(2h+1)[p][4q+i].
    #pragma unroll
    for (int e = 0; e < 16; ++e) {
        int idx = tid * 16 + e;              // 4096 elements
        int t   = idx >> 9;                  // tile (mt*2+h)
        int rem = idx & 511;
        int pp  = rem >> 5;
        int ii  = rem & 31;
        int c   = (t & 1) * 32 + ((ii & 7) >> 2) * 16 + ((ii >> 3) << 2) + (ii & 3);
        W2L[t * 640 + pp * 40 + ii] =
            (_Float16)pos_w2[((t >> 1) * 16 + pp) * 64 + c];
    }

    // ---- stage produce-side weights in block-shared LDS (rows stride 20h) ----
    if (tid < 64) {
        const int c = tid;
        float sp = pos_g[c] * rsqrtf(pos_v[c] + EPSV);
        float bp = pos_b[c] - pos_m[c] * sp;
        _Float16* row = WH + (c >> 4) * 320 + (c & 15) * 20;
        for (int k = 0; k < 20; ++k) {
            float v = (k >= 3 && k < 6) ? pos_w1[c * 3 + (k - 3)] * sp
                                        : ((k == 6) ? bp : 0.f);
            row[k] = (_Float16)v;
        }
        PB2[c] = pos_b2[c];
    } else if (tid < 80) {
        const int j = tid - 64;
        float sa = attn_g[j] * rsqrtf(attn_v[j] + EPSV);
        float ba = attn_b[j] - attn_m[j] * sa;
        _Float16* row = WH + 1280 + j * 20;
        for (int k = 0; k < 20; ++k)
            row[k] = (_Float16)((k < 6) ? attn_w1[j * 6 + k] * sa
                                        : ((k == 6) ? ba : 0.f));
    } else if (tid < 96) {
        const int j = tid - 80;
        float sg = gate_g[j] * rsqrtf(gate_v[j] + EPSV);
        float bg = gate_b[j] - gate_m[j] * sg;
        _Float16* row = WH + 1600 + j * 20;
        for (int k = 0; k < 20; ++k)
            row[k] = (_Float16)((k < 6) ? gate_w1[j * 6 + k] * sg
                                        : ((k == 6) ? bg : 0.f));
    }

    // ---- persistent A-frags: WTf/WA2f (2 VGPRs each) + WG2f broadcast ----
    v4h WTf[4], WA2f[4], WG2f;
    #pragma unroll
    for (int mt = 0; mt < 4; ++mt) {
        const int ch = mt * 16 + p;
        #pragma unroll
        for (int i = 0; i < 4; ++i)
            WA2f[mt][i] = (_Float16)attn_w2[ch * 16 + q * 4 + i];
        float st = trans_g[ch] * rsqrtf(trans_v[ch] + EPSV);
        float bt = trans_b[ch] - trans_m[ch] * st;
        #pragma unroll
        for (int i = 0; i < 4; ++i) {
            int k = q * 4 + i;
            float v = (k < 6) ? trans_w[ch * 6 + k] * st : ((k == 6) ? bt : 0.f);
            WTf[mt][i] = (_Float16)v;
        }
    }
    #pragma unroll
    for (int i = 0; i < 4; ++i)
        WG2f[i] = (_Float16)gate_w2[4 * q + i];   // A[row][k]=gate_w2[k] broadcast
    const float gb2v = gate_b2[0];

    __syncthreads();   // W2L/WH/PB2 visible to all waves

    const _Float16* const WP1p = WH + p * 20 + q * 4;          // + mt*320
    const _Float16* const WA1p = WH + 1280 + p * 20 + q * 4;
    const _Float16* const WG1p = WH + 1600 + p * 20 + q * 4;
    const _Float16* const W2Lp = W2L + p * 40 + q * 8;         // + tile*640
    const float* const    PB2p = PB2 + 4 * q;                  // + mt*16

    const v4f zero = {0.f, 0.f, 0.f, 0.f};
    v4f den[4], num[4], cmx[4];
    #pragma unroll
    for (int mt = 0; mt < 4; ++mt) {
        den[mt] = zero; num[mt] = zero;
        cmx[mt] = (v4f){-3.4e38f, -3.4e38f, -3.4e38f, -3.4e38f};
    }

    // ---- per-lane channel streams (only the 4 this lane consumes) ----
    const float* xb = x + ((size_t)(b * 6) * 8192 + n) * 20;
    const int hi = q & 1;   // q>=2 dups q&1 (A-side k>=8 rows are zero)
    const float* const s0p = xb + (size_t)(hi ? 4 : 0) * 163840;
    const float* const s1p = xb + (size_t)(hi ? 5 : 1) * 163840;
    const float* const s2p = xb + (size_t)(hi ? 4 : 2) * 163840;  // hi: L1 dup
    const float* const s3p = xb + (size_t)(hi ? 5 : 3) * 163840;  // hi: L1 dup

    // build v4h B-frag; hi lanes' high half is the constant (1.0, 0.0)
    auto mk = [&](float a, float bb, float cc, float dd) -> v4h {
        v2h lo = pk(a, bb);
        v2h hh = pk(cc, dd);
        if (hi) { union { unsigned u; v2h h; } t; t.u = 0x00003C00u; hh = t.h; }
        return (v4h){lo.x, lo.y, hh.x, hh.y};
    };

    float c0 = s0p[0], c1 = s1p[0], c2 = s2p[0], c3 = s3p[0];

    #pragma unroll 1
    for (int k = 0; k < 20; ++k) {
        // prevent LICM from hoisting in-loop LDS reads into registers
        asm volatile("" ::: "memory");

        v4h xv = mk(c0, c1, c2, c3);
        if (k < 19) {
            c0 = s0p[k + 1]; c1 = s1p[k + 1];
            c2 = s2p[k + 1]; c3 = s3p[k + 1];
        }

        // ---- hidden layers: MFMA outputs stay in registers (C==B layout) ----
        v4h phB[4];
        #pragma unroll
        for (int mt = 0; mt < 4; ++mt) {
            v4f php = MFMA16(*(const v4h*)(WP1p + mt * 320), xv, zero);
            union { v4h v; v2h h[2]; } u;
            u.h[0] = lreluh2(pk(php[0], php[1]));
            u.h[1] = lreluh2(pk(php[2], php[3]));
            phB[mt] = u.v;
        }
        v4f ahp = MFMA16(*(const v4h*)WA1p, xv, zero);
        union { v4h v; v2h h[2]; } ua;
        ua.h[0] = lreluh2(pk(ahp[0], ahp[1]));
        ua.h[1] = lreluh2(pk(ahp[2], ahp[3]));
        const v4h ahB = ua.v;

        // gate: MFMA reduction (broadcast A) -> every lane gets its col's logit
        v4f ghp = MFMA16(*(const v4h*)WG1p, xv, zero);
        union { v4h v; v2h h[2]; } ug;
        ug.h[0] = lreluh2(pk(ghp[0], ghp[1]));
        ug.h[1] = lreluh2(pk(ghp[2], ghp[3]));
        v4f gav = MFMA16(WG2f, ug.v, zero);
        const float gate = 1.f / (1.f + __expf(-(gav[0] + gb2v)));

        // ---- consume: depth-2 MFMA reduction tree per output tile ----
        #pragma unroll
        for (int mt = 0; mt < 4; ++mt) {
            union { v8h v; v4h h[2]; } w2a, w2b;
            w2a.v = *(const v8h*)(W2Lp + (mt * 2 + 0) * 640);  // ck0 | ck1
            w2b.v = *(const v8h*)(W2Lp + (mt * 2 + 1) * 640);  // ck2 | ck3
            v4f peA = MFMA16(w2a.h[0], phB[0], *(const v4f*)(PB2p + mt * 16));
            peA = MFMA16(w2a.h[1], phB[1], peA);
            v4f peB = MFMA16(w2b.h[0], phB[2], zero);
            peB = MFMA16(w2b.h[1], phB[3], peB);
            v4f la  = MFMA16(WA2f[mt], ahB, zero);   // attn 2nd layer
            v4f tfa = MFMA16(WTf[mt], xv, zero);     // trans path
            v4f posenc = peA + peB;
            v4f tfv = lrelu4(tfa) + posenc;
            v4f lg  = posenc + la;                   // attn logits
            v4f e;
            #pragma unroll
            for (int r = 0; r < 4; ++r) e[r] = __expf(lg[r]);
            den[mt] += e;
            num[mt] += tfv * e;
            cmx[mt] = __builtin_elementwise_max(cmx[mt], tfv * gate);
        }
    }

    // write out: lane owns channels mt*16 + 4q + r for its point n
    #pragma unroll
    for (int mt = 0; mt < 4; ++mt) {
        #pragma unroll
        for (int r = 0; r < 4; ++r) {
            const int ch = mt * 16 + 4 * q + r;
            out[((size_t)(b * 64 + ch)) * 8192 + n] =
                num[mt][r] / den[mt][r] + cmx[mt][r];
        }
    }
}

extern "C" void kernel_launch(void* const* d_in, const int* in_sizes, int n_in,
                              void* d_out, int out_size, void* d_ws, size_t ws_size,
                              hipStream_t stream) {
    const float* x       = (const float*)d_in[0];
    const float* trans_w = (const float*)d_in[1];
    const float* trans_g = (const float*)d_in[2];
    const float* trans_b = (const float*)d_in[3];
    const float* trans_m = (const float*)d_in[4];
    const float* trans_v = (const float*)d_in[5];
    const float* pos_w1  = (const float*)d_in[6];
    const float* pos_g   = (const float*)d_in[7];
    const float* pos_b   = (const float*)d_in[8];
    const float* pos_m   = (const float*)d_in[9];
    const float* pos_v   = (const float*)d_in[10];
    const float* pos_w2  = (const float*)d_in[11];
    const float* pos_b2  = (const float*)d_in[12];
    const float* gate_w1 = (const float*)d_in[13];
    const float* gate_g  = (const float*)d_in[14];
    const float* gate_b  = (const float*)d_in[15];
    const float* gate_m  = (const float*)d_in[16];
    const float* gate_v  = (const float*)d_in[17];
    const float* gate_w2 = (const float*)d_in[18];
    const float* gate_b2 = (const float*)d_in[19];
    const float* attn_w1 = (const float*)d_in[20];
    const float* attn_g  = (const float*)d_in[21];
    const float* attn_b  = (const float*)d_in[22];
    const float* attn_m  = (const float*)d_in[23];
    const float* attn_v  = (const float*)d_in[24];
    const float* attn_w2 = (const float*)d_in[25];
    const float* attn_b2 = (const float*)d_in[26];
    float* out = (float*)d_out;

    // 8 b * 128 blocks/b; block = 4 waves * 16 points
    gsl_mfma<<<1024, 256, 0, stream>>>(
        x, trans_w, trans_g, trans_b, trans_m, trans_v,
        pos_w1, pos_g, pos_b, pos_m, pos_v, pos_w2, pos_b2,
        gate_w1, gate_g, gate_b, gate_m, gate_v, gate_w2, gate_b2,
        attn_w1, attn_g, attn_b, attn_m, attn_v, attn_w2, attn_b2,
        out);
}

// Round 8
// 170.457 us; speedup vs baseline: 2.0621x; 1.0697x over previous
//
#include <hip/hip_runtime.h>
#include <math.h>

#define NEG 0.2f
#define EPSV 1e-5f

typedef _Float16 v8h __attribute__((ext_vector_type(8)));
typedef _Float16 v4h __attribute__((ext_vector_type(4)));
typedef _Float16 v2h __attribute__((ext_vector_type(2)));
typedef __fp16   f16x2 __attribute__((ext_vector_type(2)));
typedef float    v4f __attribute__((ext_vector_type(4)));

__device__ __forceinline__ float lrelu(float v) { return fmaxf(v, NEG * v); }
__device__ __forceinline__ v4f lrelu4(v4f v) {
    return __builtin_elementwise_max(v, v * NEG);
}
__device__ __forceinline__ v2h lreluh2(v2h v) {
    return __builtin_elementwise_max(v, v * (_Float16)NEG);
}

// cvt_pkrtz returns __fp16x2; bit-cast to _Float16x2 (same layout)
__device__ __forceinline__ v2h pk(float a, float b) {
    union { f16x2 i; v2h o; } u;
    u.i = __builtin_amdgcn_cvt_pkrtz(a, b);
    return u.o;
}

#define MFMA32(a, b, c) __builtin_amdgcn_mfma_f32_16x16x32_f16((a), (b), (c), 0, 0, 0)
#define MFMA16(a, b, c) __builtin_amdgcn_mfma_f32_16x16x16f16((a), (b), (c), 0, 0, 0)

// Round 21 (resubmit after infra failure). R20 lesson: chain through MFMA C
// operand (VALU re-join of MFMA results stalls on read hazards). Two fixes:
// (1) pos_enc back to 8x MFMA32 (K=32) WITHOUT any LDS round-trip or
//     permutes: a K=32 B-frag needs lane(p,q) to hold k=8q+j; defining the
//     k->hidden-channel map as h = (j<4 ? 4q+j : 16+4q+j-4) makes the
//     CONCAT of two packed K=16 MFMA outputs (phB[t]|phB[t+1]) a valid
//     B-frag. The matching column permutation is absorbed into W2L staging.
//     16 MFMA16 -> 8 MFMA32: same FLOPs, half the matrix-pipe slots
//     (R17 measured MFMA16 and MFMA32 cost the same slot).
// (2) lane-linear LDS layouts: every wave reads ALL of W2L/WHL each iter, so
//     store per-lane chunks wave-contiguously (tile*1024B + lane*16B).
//     Conflict-free by construction; kills the 2.7M stride-40 conflicts.
__global__ __launch_bounds__(256, 4)
void gsl_mfma(const float* __restrict__ x,
              const float* __restrict__ trans_w, const float* __restrict__ trans_g,
              const float* __restrict__ trans_b, const float* __restrict__ trans_m,
              const float* __restrict__ trans_v,
              const float* __restrict__ pos_w1, const float* __restrict__ pos_g,
              const float* __restrict__ pos_b, const float* __restrict__ pos_m,
              const float* __restrict__ pos_v, const float* __restrict__ pos_w2,
              const float* __restrict__ pos_b2,
              const float* __restrict__ gate_w1, const float* __restrict__ gate_g,
              const float* __restrict__ gate_b, const float* __restrict__ gate_m,
              const float* __restrict__ gate_v, const float* __restrict__ gate_w2,
              const float* __restrict__ gate_b2,
              const float* __restrict__ attn_w1, const float* __restrict__ attn_g,
              const float* __restrict__ attn_b, const float* __restrict__ attn_m,
              const float* __restrict__ attn_v, const float* __restrict__ attn_w2,
              const float* __restrict__ attn_b2,
              float* __restrict__ out)
{
    __shared__ _Float16 WHL[1536];  // 6 sets x 64 lanes x v4h (lane-linear)
                                    // sets 0-3: WP1 mt, 4: WA1, 5: WG1
    __shared__ _Float16 W2L[4096];  // 8 tiles x 64 lanes x v8h (lane-linear)
    __shared__ float    PB2[64];

    const int tid  = threadIdx.x;
    const int wv   = tid >> 6;
    const int lane = tid & 63;
    const int p    = lane & 15;
    const int q    = lane >> 4;

    const int b  = blockIdx.x >> 7;
    const int n0 = ((blockIdx.x & 127) << 6) | (wv << 4);
    const int n  = n0 | p;

    // ---- stage pos_w2 K=32 A-frags into W2L (lane-linear) ----
    // tile t = mt*2 + half; lane l=(qk*16+pp) elem j:
    //   A[m=pp][k=8qk+j] = W2[ch=(t>>1)*16+pp][ (t&1)*32 + h_local ]
    //   h_local = j<4 ? 4qk+j : 16 + 4qk + (j-4)   (concat-of-two-tiles map)
    #pragma unroll
    for (int e = 0; e < 16; ++e) {
        int idx = tid * 16 + e;              // 4096 elements
        int t   = idx >> 9;
        int rem = idx & 511;
        int l   = rem >> 3;
        int j   = rem & 7;
        int qk  = l >> 4;
        int pp  = l & 15;
        int hl  = (j < 4) ? (4 * qk + j) : (16 + 4 * qk + (j - 4));
        W2L[t * 512 + l * 8 + j] =
            (_Float16)pos_w2[((t >> 1) * 16 + pp) * 64 + (t & 1) * 32 + hl];
    }

    // ---- stage produce-side weight A-frags into WHL (lane-linear) ----
    if (tid < 64) {
        const int c = tid;                   // pos hidden channel
        float sp = pos_g[c] * rsqrtf(pos_v[c] + EPSV);
        float bp = pos_b[c] - pos_m[c] * sp;
        const int mt = c >> 4, pp = c & 15;
        for (int k = 0; k < 16; ++k) {
            float v = (k >= 3 && k < 6) ? pos_w1[c * 3 + (k - 3)] * sp
                                        : ((k == 6) ? bp : 0.f);
            WHL[mt * 256 + ((k >> 2) * 16 + pp) * 4 + (k & 3)] = (_Float16)v;
        }
        PB2[c] = pos_b2[c];
    } else if (tid < 80) {
        const int j = tid - 64;              // attn hidden channel
        float sa = attn_g[j] * rsqrtf(attn_v[j] + EPSV);
        float ba = attn_b[j] - attn_m[j] * sa;
        for (int k = 0; k < 16; ++k) {
            float v = (k < 6) ? attn_w1[j * 6 + k] * sa : ((k == 6) ? ba : 0.f);
            WHL[1024 + ((k >> 2) * 16 + j) * 4 + (k & 3)] = (_Float16)v;
        }
    } else if (tid < 96) {
        const int j = tid - 80;              // gate hidden channel
        float sg = gate_g[j] * rsqrtf(gate_v[j] + EPSV);
        float bg = gate_b[j] - gate_m[j] * sg;
        for (int k = 0; k < 16; ++k) {
            float v = (k < 6) ? gate_w1[j * 6 + k] * sg : ((k == 6) ? bg : 0.f);
            WHL[1280 + ((k >> 2) * 16 + j) * 4 + (k & 3)] = (_Float16)v;
        }
    }

    // ---- persistent A-frags: WTf/WA2f (2 VGPRs each) + WG2f broadcast ----
    v4h WTf[4], WA2f[4], WG2f;
    #pragma unroll
    for (int mt = 0; mt < 4; ++mt) {
        const int ch = mt * 16 + p;
        #pragma unroll
        for (int i = 0; i < 4; ++i)
            WA2f[mt][i] = (_Float16)attn_w2[ch * 16 + q * 4 + i];
        float st = trans_g[ch] * rsqrtf(trans_v[ch] + EPSV);
        float bt = trans_b[ch] - trans_m[ch] * st;
        #pragma unroll
        for (int i = 0; i < 4; ++i) {
            int k = q * 4 + i;
            float v = (k < 6) ? trans_w[ch * 6 + k] * st : ((k == 6) ? bt : 0.f);
            WTf[mt][i] = (_Float16)v;
        }
    }
    #pragma unroll
    for (int i = 0; i < 4; ++i)
        WG2f[i] = (_Float16)gate_w2[4 * q + i];   // A[row][k]=gate_w2[k] broadcast
    const float gb2v = gate_b2[0];

    __syncthreads();   // W2L/WHL/PB2 visible to all waves

    const _Float16* const WHLp = WHL + lane * 4;   // + set*256
    const _Float16* const W2Lp = W2L + lane * 8;   // + tile*512
    const float* const    PB2p = PB2 + 4 * q;      // + mt*16

    const v4f zero = {0.f, 0.f, 0.f, 0.f};
    v4f den[4], num[4], cmx[4];
    #pragma unroll
    for (int mt = 0; mt < 4; ++mt) {
        den[mt] = zero; num[mt] = zero;
        cmx[mt] = (v4f){-3.4e38f, -3.4e38f, -3.4e38f, -3.4e38f};
    }

    // ---- per-lane channel streams (only the 4 this lane consumes) ----
    const float* xb = x + ((size_t)(b * 6) * 8192 + n) * 20;
    const int hi = q & 1;   // q>=2 dups q&1 (A-side k>=8 rows are zero)
    const float* const s0p = xb + (size_t)(hi ? 4 : 0) * 163840;
    const float* const s1p = xb + (size_t)(hi ? 5 : 1) * 163840;
    const float* const s2p = xb + (size_t)(hi ? 4 : 2) * 163840;  // hi: L1 dup
    const float* const s3p = xb + (size_t)(hi ? 5 : 3) * 163840;  // hi: L1 dup

    // build v4h B-frag; hi lanes' high half is the constant (1.0, 0.0)
    auto mk = [&](float a, float bb, float cc, float dd) -> v4h {
        v2h lo = pk(a, bb);
        v2h hh = pk(cc, dd);
        if (hi) { union { unsigned u; v2h h; } t; t.u = 0x00003C00u; hh = t.h; }
        return (v4h){lo.x, lo.y, hh.x, hh.y};
    };

    float c0 = s0p[0], c1 = s1p[0], c2 = s2p[0], c3 = s3p[0];

    #pragma unroll 1
    for (int k = 0; k < 20; ++k) {
        // prevent LICM from hoisting in-loop LDS reads into registers
        asm volatile("" ::: "memory");

        v4h xv = mk(c0, c1, c2, c3);
        if (k < 19) {
            c0 = s0p[k + 1]; c1 = s1p[k + 1];
            c2 = s2p[k + 1]; c3 = s3p[k + 1];
        }

        // ---- hidden layers: packed outputs become K=32 B-frags directly ----
        union { v8h v; v4h h[2]; } uA, uC;   // tiles 0|1 and 2|3 concatenated
        #pragma unroll
        for (int mt = 0; mt < 4; ++mt) {
            v4f php = MFMA16(*(const v4h*)(WHLp + mt * 256), xv, zero);
            v2h e0 = lreluh2(pk(php[0], php[1]));
            v2h e1 = lreluh2(pk(php[2], php[3]));
            v4h pkd = (v4h){e0.x, e0.y, e1.x, e1.y};
            if (mt < 2) uA.h[mt] = pkd; else uC.h[mt - 2] = pkd;
        }
        v4f ahp = MFMA16(*(const v4h*)(WHLp + 1024), xv, zero);
        union { v4h v; v2h h[2]; } ua;
        ua.h[0] = lreluh2(pk(ahp[0], ahp[1]));
        ua.h[1] = lreluh2(pk(ahp[2], ahp[3]));
        const v4h ahB = ua.v;

        // gate: MFMA reduction (broadcast A) -> every lane gets its col's logit
        v4f ghp = MFMA16(*(const v4h*)(WHLp + 1280), xv, zero);
        union { v4h v; v2h h[2]; } ug;
        ug.h[0] = lreluh2(pk(ghp[0], ghp[1]));
        ug.h[1] = lreluh2(pk(ghp[2], ghp[3]));
        v4f gav = MFMA16(WG2f, ug.v, zero);
        const float gate = 1.f / (1.f + __expf(-(gav[0] + gb2v)));

        // ---- consume: pos_enc as 2x chained K=32 MFMA per output tile ----
        #pragma unroll
        for (int mt = 0; mt < 4; ++mt) {
            v8h w2a = *(const v8h*)(W2Lp + (mt * 2 + 0) * 512);  // h 0..31
            v8h w2b = *(const v8h*)(W2Lp + (mt * 2 + 1) * 512);  // h 32..63
            v4f pe = MFMA32(w2a, uA.v, *(const v4f*)(PB2p + mt * 16));
            pe = MFMA32(w2b, uC.v, pe);
            v4f tfa = MFMA16(WTf[mt], xv, zero);
            v4f tfv = lrelu4(tfa) + pe;
            pe = MFMA16(WA2f[mt], ahB, pe);   // attn logits (K=16)
            v4f e;
            #pragma unroll
            for (int r = 0; r < 4; ++r) e[r] = __expf(pe[r]);
            den[mt] += e;
            num[mt] += tfv * e;
            cmx[mt] = __builtin_elementwise_max(cmx[mt], tfv * gate);
        }
    }

    // write out: lane owns channels mt*16 + 4q + r for its point n
    #pragma unroll
    for (int mt = 0; mt < 4; ++mt) {
        #pragma unroll
        for (int r = 0; r < 4; ++r) {
            const int ch = mt * 16 + 4 * q + r;
            out[((size_t)(b * 64 + ch)) * 8192 + n] =
                num[mt][r] / den[mt][r] + cmx[mt][r];
        }
    }
}

extern "C" void kernel_launch(void* const* d_in, const int* in_sizes, int n_in,
                              void* d_out, int out_size, void* d_ws, size_t ws_size,
                              hipStream_t stream) {
    const float* x       = (const float*)d_in[0];
    const float* trans_w = (const float*)d_in[1];
    const float* trans_g = (const float*)d_in[2];
    const float* trans_b = (const float*)d_in[3];
    const float* trans_m = (const float*)d_in[4];
    const float* trans_v = (const float*)d_in[5];
    const float* pos_w1  = (const float*)d_in[6];
    const float* pos_g   = (const float*)d_in[7];
    const float* pos_b   = (const float*)d_in[8];
    const float* pos_m   = (const float*)d_in[9];
    const float* pos_v   = (const float*)d_in[10];
    const float* pos_w2  = (const float*)d_in[11];
    const float* pos_b2  = (const float*)d_in[12];
    const float* gate_w1 = (const float*)d_in[13];
    const float* gate_g  = (const float*)d_in[14];
    const float* gate_b  = (const float*)d_in[15];
    const float* gate_m  = (const float*)d_in[16];
    const float* gate_v  = (const float*)d_in[17];
    const float* gate_w2 = (const float*)d_in[18];
    const float* gate_b2 = (const float*)d_in[19];
    const float* attn_w1 = (const float*)d_in[20];
    const float* attn_g  = (const float*)d_in[21];
    const float* attn_b  = (const float*)d_in[22];
    const float* attn_m  = (const float*)d_in[23];
    const float* attn_v  = (const float*)d_in[24];
    const float* attn_w2 = (const float*)d_in[25];
    const float* attn_b2 = (const float*)d_in[26];
    float* out = (float*)d_out;

    // 8 b * 128 blocks/b; block = 4 waves * 16 points
    gsl_mfma<<<1024, 256, 0, stream>>>(
        x, trans_w, trans_g, trans_b, trans_m, trans_v,
        pos_w1, pos_g, pos_b, pos_m, pos_v, pos_w2, pos_b2,
        gate_w1, gate_g, gate_b, gate_m, gate_v, gate_w2, gate_b2,
        attn_w1, attn_g, attn_b, attn_m, attn_v, attn_w2, attn_b2,
        out);
}